// Round 16
// baseline (429.304 us; speedup 1.0000x reference)
//
#include <hip/hip_runtime.h>
#include <hip/hip_bf16.h>

typedef unsigned short u16;
typedef unsigned int u32;
typedef unsigned long long u64;
typedef __attribute__((ext_vector_type(8))) short short8;
typedef __attribute__((ext_vector_type(4))) float f32x4;

#define NB 32      // trees
#define NN 128     // nodes per tree
#define HH 300     // hidden
#define NV 32000   // vocab
#define KP 320     // padded K; hb16 row stride
#define KX 352     // padded RD+E
#define XGS 1280   // xg row stride

// scan: 32 trees x 15 slices, level-synchronous, MFMA MV (R11-R15 proven)
#define NSLICE 15
#define UPS 20
#define NROWS 80
#define TPBS 320
#define GMAXN 16
#define LDW 328

#define A_LD(p)     __hip_atomic_load((p), __ATOMIC_RELAXED, __HIP_MEMORY_SCOPE_AGENT)
#define A_ST(p, v)  __hip_atomic_store((p), (v), __ATOMIC_RELAXED, __HIP_MEMORY_SCOPE_AGENT)
#define A_ADD(p, v) __hip_atomic_fetch_add((p), (v), __ATOMIC_RELAXED, __HIP_MEMORY_SCOPE_AGENT)

__device__ __forceinline__ float sigm(float x) { return 1.f / (1.f + __expf(-x)); }
__device__ __forceinline__ float tanh_f(float x) {
    float e = __expf(2.f * x);
    return 1.f - 2.f / (e + 1.f);
}
__device__ __forceinline__ u16 f2bf(float f) {
    __hip_bfloat16 b = __float2bfloat16(f);
    return *reinterpret_cast<u16*>(&b);
}
__device__ __forceinline__ void gl_lds16(const u16* gsrc, u16* ldst) {
    __builtin_amdgcn_global_load_lds(
        (const __attribute__((address_space(1))) void*)gsrc,
        (__attribute__((address_space(3))) void*)ldst, 16, 0, 0);
}

// Merged prelude: hb16 init, lvl_done zero, Wihp pack, Wp16 pack, Xbf gather,
// plus level-schedule build (block 0, one thread per tree, local scratch arrays).
// Levels sorted early-parent-first with lvl_split = #early (parent level < l-1).
__global__ __launch_bounds__(256) void k_prelude(const float* __restrict__ rh,
                                                 const int* __restrict__ relations,
                                                 const int* __restrict__ prev_words,
                                                 const float* __restrict__ rel_emb,
                                                 const float* __restrict__ emb,
                                                 const float* __restrict__ W_ih,
                                                 const float* __restrict__ W_hh,
                                                 const int* __restrict__ parents,
                                                 u16* __restrict__ hb16,
                                                 int* __restrict__ lvl_done,
                                                 u16* __restrict__ Wihp,
                                                 u16* __restrict__ Wp16,
                                                 u16* __restrict__ Xbf,
                                                 int* __restrict__ lvl_nodes,
                                                 int* __restrict__ lvl_cnt,
                                                 int* __restrict__ lvl_start,
                                                 int* __restrict__ lvl_split,
                                                 int* __restrict__ nlev) {
    const int stride = gridDim.x * blockDim.x;
    const int idx = blockIdx.x * blockDim.x + threadIdx.x;
    for (int e = idx; e < NB * 129 * 20; e += stride) {
        int row = e / 20, c = 300 + (e - row * 20);
        hb16[(size_t)row * KP + c] = 0;
    }
    for (int e = idx; e < NB * HH; e += stride) {
        int b = e / HH, u = e - b * HH;
        hb16[(size_t)(b * 129) * KP + u] = f2bf(rh[e]);
    }
    for (int e = idx; e < NB * NN; e += stride) lvl_done[e] = 0;
    for (int n = idx; n < 1280 * KX; n += stride) {
        int r = n / KX, k = n - r * KX;
        float v = (r < 1200 && k < 350) ? W_ih[r * 350 + k] : 0.f;
        Wihp[n] = f2bf(v);
    }
    for (int m = idx; m < NSLICE * NROWS * LDW; m += stride) {
        int s = m / (NROWS * LDW);
        int rem = m - s * (NROWS * LDW);
        int r = rem / LDW, k = rem - r * LDW;
        int g = r / UPS, ul = r - g * UPS;
        int grow = g * HH + s * UPS + ul;
        float v = (k < HH) ? W_hh[grow * HH + k] : 0.f;
        Wp16[m] = f2bf(v);
    }
    for (int e = idx; e < NB * NN * KX; e += stride) {
        int node = e / KX, c = e - node * KX;
        float v = 0.f;
        if (c < 50) v = rel_emb[relations[node] * 50 + c];
        else if (c < 350) v = emb[(size_t)prev_words[node] * 300 + (c - 50)];
        Xbf[e] = f2bf(v);
    }
    // level schedule (one thread per tree; local scratch arrays)
    if (blockIdx.x == 0 && threadIdx.x < NB) {
        const int tb = threadIdx.x;
        const int* par = parents + tb * NN;
        int dep[NN], cnt[NN], st[NN], ec[NN], ce[NN], cl[NN];
        for (int l = 0; l < NN; ++l) { cnt[l] = 0; ec[l] = 0; }
        int md = 0;
        for (int i = 0; i < NN; ++i) {
            int p = par[i];
            int d = (p < 0) ? 0 : dep[p] + 1;
            dep[i] = d;
            cnt[d]++;
            if (p < 0 || dep[p] < d - 1) ec[d]++;
            md = max(md, d);
        }
        nlev[tb] = md + 1;
        int run = 0;
        for (int l = 0; l < NN; ++l) {
            st[l] = run;
            lvl_start[tb * NN + l] = run;
            lvl_cnt[tb * NN + l] = cnt[l];
            lvl_split[tb * NN + l] = ec[l];
            ce[l] = run;
            cl[l] = run + ec[l];
            run += cnt[l];
        }
        for (int i = 0; i < NN; ++i) {
            int d = dep[i], p = par[i];
            bool early = (p < 0) || (dep[p] < d - 1);
            lvl_nodes[tb * NN + (early ? ce[d]++ : cl[d]++)] = i;
        }
    }
}

// xgemm (blocks 0..319) + W_out->bf16 cast (blocks 320..831, independent).
__global__ __launch_bounds__(256) void k_xgemm_cast(const u16* __restrict__ Xbf,
                                                    const u16* __restrict__ Wihp,
                                                    const float* __restrict__ b_ih,
                                                    float* __restrict__ xg,
                                                    const float* __restrict__ W_out,
                                                    u16* __restrict__ Bbf) {
    __shared__ __align__(16) u16 As[128 * 40];
    __shared__ __align__(16) u16 Bs[128 * 40];
    const int tid = threadIdx.x;
    if (blockIdx.x >= 320) {
        // ---- cast: Bbf[32000][320] bf16, zero-padded K ----
        const int cidx = (blockIdx.x - 320) * 256 + tid;
        const int cstride = 512 * 256;
        u64* Bq = (u64*)Bbf;
        for (int e = cidx; e < NV * KP / 4; e += cstride) {
            const int c4 = e * 4;
            const int v = c4 / KP, k = c4 - v * KP;
            const float* wr = W_out + (size_t)v * HH;
            float x0 = (k + 0 < HH) ? wr[k + 0] : 0.f;
            float x1 = (k + 1 < HH) ? wr[k + 1] : 0.f;
            float x2 = (k + 2 < HH) ? wr[k + 2] : 0.f;
            float x3 = (k + 3 < HH) ? wr[k + 3] : 0.f;
            Bq[e] = (u64)f2bf(x0) | ((u64)f2bf(x1) << 16) |
                    ((u64)f2bf(x2) << 32) | ((u64)f2bf(x3) << 48);
        }
        return;
    }
    // ---- xgemm: xg[4096][1280] = X @ Wihp^T + b_ih (R12-proven path) ----
    const int lane = tid & 63, wv = tid >> 6;
    const int wm = wv >> 1, wn = wv & 1;
    const int mblk = blockIdx.x % 32, nblk = blockIdx.x / 32;
    const u16* Ag = Xbf + (size_t)mblk * 128 * KX;
    const u16* Bg = Wihp + (size_t)nblk * 128 * KX;
    f32x4 acc[4][4] = {};
    const int lrow = lane & 15, lseg = lane >> 4;
    for (int kk = 0; kk < KX; kk += 32) {
#pragma unroll
        for (int q = 0; q < 2; ++q) {
            int s = tid + q * 256;
            int r = s >> 2, seg = s & 3;
            *(uint4*)&As[r * 40 + seg * 8] = *(const uint4*)&Ag[(size_t)r * KX + kk + seg * 8];
            *(uint4*)&Bs[r * 40 + seg * 8] = *(const uint4*)&Bg[(size_t)r * KX + kk + seg * 8];
        }
        __syncthreads();
        short8 av[4], bv[4];
#pragma unroll
        for (int i = 0; i < 4; ++i) {
            av[i] = *(const short8*)&As[(wm * 64 + i * 16 + lrow) * 40 + lseg * 8];
            bv[i] = *(const short8*)&Bs[(wn * 64 + i * 16 + lrow) * 40 + lseg * 8];
        }
#pragma unroll
        for (int i = 0; i < 4; ++i)
#pragma unroll
            for (int j = 0; j < 4; ++j)
                acc[i][j] = __builtin_amdgcn_mfma_f32_16x16x32_bf16(bv[j], av[i], acc[i][j],
                                                                    0, 0, 0);
        __syncthreads();
    }
#pragma unroll
    for (int i = 0; i < 4; ++i) {
        const int row = mblk * 128 + wm * 64 + i * 16 + lrow;
        float* orow = xg + (size_t)row * XGS;
#pragma unroll
        for (int j = 0; j < 4; ++j) {
            const int col = nblk * 128 + wn * 64 + j * 16 + lseg * 4;
            f32x4 v = acc[i][j];
            if (col < 1200) {
                f32x4 bo = *(const f32x4*)&b_ih[col];
                v[0] += bo[0]; v[1] += bo[1]; v[2] += bo[2]; v[3] += bo[3];
            }
            *(f32x4*)&orow[col] = v;
        }
    }
}

// Level-synchronous MFMA scan with early-parent prefetch: pass-0 rows of the
// next level whose parent level < l (final before rendezvous l) are staged
// BEFORE the rendezvous, overlapping the ~1us MALL stage latency with the
// ~1us rendezvous poll. Compute/publish protocol byte-identical to R11-R15.
__global__ __launch_bounds__(TPBS) void k_scan(const int* __restrict__ parents,
                                               const u16* __restrict__ Wp16,
                                               const float* __restrict__ xg,
                                               const float* __restrict__ b_hh,
                                               const float* __restrict__ rh,
                                               u16* __restrict__ hb16,
                                               const int* __restrict__ lvl_nodes,
                                               const int* __restrict__ lvl_cnt,
                                               const int* __restrict__ lvl_start,
                                               const int* __restrict__ lvl_split,
                                               const int* __restrict__ nlev,
                                               int* __restrict__ lvl_done) {
    __shared__ __align__(16) u16 Wl[NROWS * LDW];
    __shared__ __align__(16) u16 hs[GMAXN * LDW];
    __shared__ __align__(16) float gates[GMAXN * 82];
    __shared__ float c_lds[129 * UPS];
    __shared__ int nid_s[GMAXN], par_s[GMAXN];

    const int t = threadIdx.x;
    const int b = blockIdx.x / NSLICE;
    const int s = blockIdx.x % NSLICE;
    const int lane = t & 63, wv = t >> 6;
    const int lrow = lane & 15, lk = lane >> 4;
    const int base = b * NN;

    {
        const u64* src = (const u64*)(Wp16 + (size_t)s * NROWS * LDW);
        u64* dst = (u64*)Wl;
        for (int e = t; e < NROWS * LDW / 4; e += TPBS) dst[e] = src[e];
    }
    if (t < UPS) c_lds[t] = rh[b * HH + s * UPS + t];

    // preload + stage level-0 pass-0 (all roots; parent slot 0 ready)
    {
        const int gc0 = min(GMAXN, lvl_cnt[base]);
        if (t < gc0) {
            int i = lvl_nodes[base + t];
            nid_s[t] = i;
            par_s[t] = parents[base + i];
        }
        __syncthreads();
        for (int e = t; e < gc0 * 80; e += TPBS) {
            const int j = e / 80, q = e - j * 80;
            const u64* hrow = (const u64*)(hb16 + (size_t)(b * 129 + par_s[j] + 1) * KP);
            *(u64*)&hs[j * LDW + q * 4] = A_LD(&hrow[q]);
        }
    }

    const int nl = nlev[b];
    for (int l = 0; l < nl; ++l) {
        const int cnt = lvl_cnt[base + l];
        const int start = lvl_start[base + l];
        const int split = lvl_split[base + l];
        for (int off = 0; off < cnt; off += GMAXN) {
            const int gc = min(GMAXN, cnt - off);
            if (off == 0) {
                // ids preloaded; rows [0, es) already staged — stage the rest
                const int es = min(split, gc);
                for (int e = t; e < (gc - es) * 80; e += TPBS) {
                    const int j = es + e / 80, q = e % 80;
                    const u64* hrow = (const u64*)(hb16 +
                        (size_t)(b * 129 + par_s[j] + 1) * KP);
                    *(u64*)&hs[j * LDW + q * 4] = A_LD(&hrow[q]);
                }
            } else {
                if (t < gc) {
                    int i = lvl_nodes[base + start + off + t];
                    nid_s[t] = i;
                    par_s[t] = parents[base + i];
                }
                __syncthreads();
                for (int e = t; e < gc * 80; e += TPBS) {
                    const int j = e / 80, q = e - j * 80;
                    const u64* hrow = (const u64*)(hb16 +
                        (size_t)(b * 129 + par_s[j] + 1) * KP);
                    *(u64*)&hs[j * LDW + q * 4] = A_LD(&hrow[q]);
                }
            }
            __syncthreads();
            {
                f32x4 acc = {};
#pragma unroll
                for (int kk = 0; kk < KP; kk += 32) {
                    short8 av = *(const short8*)&hs[lrow * LDW + kk + lk * 8];
                    short8 bv = *(const short8*)&Wl[(wv * 16 + lrow) * LDW + kk + lk * 8];
                    acc = __builtin_amdgcn_mfma_f32_16x16x32_bf16(av, bv, acc, 0, 0, 0);
                }
#pragma unroll
                for (int r = 0; r < 4; ++r)
                    gates[(lk * 4 + r) * 82 + wv * 16 + lrow] = acc[r];
            }
            __syncthreads();
            if (t < 160) {
                const int j = t / 10, up = t - j * 10;
                if (j < gc) {
                    const int i = nid_s[j];
                    const int par = par_s[j];
                    const int ul0 = up * 2;
                    const float* gj = gates + j * 82;
                    const float* xgp = xg + (size_t)(base + i) * XGS + s * UPS;
                    const float* bhp = b_hh + s * UPS;
                    float hv[2];
#pragma unroll
                    for (int un = 0; un < 2; ++un) {
                        const int ul = ul0 + un;
                        float gs[4];
#pragma unroll
                        for (int g = 0; g < 4; ++g)
                            gs[g] = gj[g * UPS + ul] + xgp[g * HH + ul] + bhp[g * HH + ul];
                        const float pc = c_lds[(par + 1) * UPS + ul];
                        const float cv = sigm(gs[1]) * pc + sigm(gs[0]) * tanh_f(gs[2]);
                        hv[un] = sigm(gs[3]) * tanh_f(cv);
                        c_lds[(i + 1) * UPS + ul] = cv;
                    }
                    const u32 hp = (u32)f2bf(hv[0]) | ((u32)f2bf(hv[1]) << 16);
                    A_ST((u32*)(hb16 + (size_t)(b * 129 + i + 1) * KP + s * UPS + ul0), hp);
                }
            }
            __syncthreads();  // drains h publishes (vmcnt0) + LDS reuse safety
        }
        if (l + 1 < nl) {
            // preload next-level pass-0 ids; stage EARLY rows (parent level < l,
            // final since rendezvous l-1) BEFORE this level's rendezvous
            const int cntN = lvl_cnt[base + l + 1];
            const int startN = lvl_start[base + l + 1];
            const int gcN = min(GMAXN, cntN);
            const int esN = min(lvl_split[base + l + 1], gcN);
            if (t < gcN) {
                int i = lvl_nodes[base + startN + t];
                nid_s[t] = i;
                par_s[t] = parents[base + i];
            }
            __syncthreads();
            for (int e = t; e < esN * 80; e += TPBS) {
                const int j = e / 80, q = e - j * 80;
                const u64* hrow = (const u64*)(hb16 +
                    (size_t)(b * 129 + par_s[j] + 1) * KP);
                *(u64*)&hs[j * LDW + q * 4] = A_LD(&hrow[q]);
            }
            if (t == 0) {
                int* dp = &lvl_done[base + l];
                const int old = A_ADD(dp, 1);
                if (old != NSLICE - 1) {
                    while (A_LD(dp) < NSLICE) __builtin_amdgcn_s_sleep(1);
                }
            }
            __syncthreads();
        }
    }
}

// logits = A(hb16) @ B^T + b_out — byte-identical to R15's proven kernel.
__global__ __launch_bounds__(256) void k_gemm(const u16* __restrict__ hb16,
                                              const u16* __restrict__ Bbf,
                                              const float* __restrict__ b_out,
                                              float* __restrict__ out) {
    __shared__ __align__(16) u16 As[128 * 32];
    __shared__ __align__(16) u16 Bs[128 * 32];
    const int tid = threadIdx.x;
    const int lane = tid & 63, wv = tid >> 6;
    const int wm = wv >> 1, wn = wv & 1;
    const int bid = blockIdx.x;                  // 8000 = 32 mblk x 250 nblk
    const int newbid = (bid & 7) * 1000 + (bid >> 3);
    const int mblk = newbid & 31, nblk = newbid >> 5;
    const u16* Ag = hb16 + ((size_t)mblk * 129 + 1) * KP;
    const u16* Bg = Bbf + (size_t)nblk * 128 * KP;
    const int r0 = wv * 32 + (lane >> 2);
    const int r1 = r0 + 16;
    const int q0 = lane & 3;
    const int lk0 = (q0 - (r0 >> 1)) & 3;
    const int lk1 = (q0 - (r1 >> 1)) & 3;
    const u16* pa0 = Ag + (size_t)r0 * KP + lk0 * 8;
    const u16* pa1 = Ag + (size_t)r1 * KP + lk1 * 8;
    const u16* pb0 = Bg + (size_t)r0 * KP + lk0 * 8;
    const u16* pb1 = Bg + (size_t)r1 * KP + lk1 * 8;
    u16* lA = As + wv * 1024;
    u16* lB = Bs + wv * 1024;
    f32x4 acc[4][4] = {};
    const int lrow = lane & 15, lseg = lane >> 4;
    for (int kk = 0; kk < KP; kk += 32) {
        gl_lds16(pa0 + kk, lA);
        gl_lds16(pa1 + kk, lA + 512);
        gl_lds16(pb0 + kk, lB);
        gl_lds16(pb1 + kk, lB + 512);
        __syncthreads();
        short8 av[4], bv[4];
#pragma unroll
        for (int i = 0; i < 4; ++i) {
            const int ra = wm * 64 + i * 16 + lrow;
            const int rb = wn * 64 + i * 16 + lrow;
            av[i] = *(const short8*)&As[ra * 32 + (((lseg + (ra >> 1)) & 3) * 8)];
            bv[i] = *(const short8*)&Bs[rb * 32 + (((lseg + (rb >> 1)) & 3) * 8)];
        }
#pragma unroll
        for (int i = 0; i < 4; ++i)
#pragma unroll
            for (int j = 0; j < 4; ++j)
                acc[i][j] = __builtin_amdgcn_mfma_f32_16x16x32_bf16(bv[j], av[i], acc[i][j],
                                                                    0, 0, 0);
        __syncthreads();
    }
#pragma unroll
    for (int i = 0; i < 4; ++i) {
        const int row = mblk * 128 + wm * 64 + i * 16 + lrow;
        float* orow = out + (size_t)row * NV;
#pragma unroll
        for (int j = 0; j < 4; ++j) {
            const int col = nblk * 128 + wn * 64 + j * 16 + lseg * 4;
            f32x4 v = acc[i][j];
            f32x4 bo = *(const f32x4*)&b_out[col];
            v[0] += bo[0]; v[1] += bo[1]; v[2] += bo[2]; v[3] += bo[3];
            __builtin_nontemporal_store(v, (f32x4*)&orow[col]);
        }
    }
}

extern "C" void kernel_launch(void* const* d_in, const int* in_sizes, int n_in,
                              void* d_out, int out_size, void* d_ws, size_t ws_size,
                              hipStream_t stream) {
    const float* root_hidden = (const float*)d_in[0];
    const int* relations = (const int*)d_in[1];
    const int* prev_words = (const int*)d_in[2];
    const int* parents = (const int*)d_in[3];
    const float* emb = (const float*)d_in[4];
    const float* rel_emb = (const float*)d_in[5];
    const float* W_ih = (const float*)d_in[6];
    const float* W_hh = (const float*)d_in[7];
    const float* b_ih = (const float*)d_in[8];
    const float* b_hh = (const float*)d_in[9];
    const float* W_out = (const float*)d_in[10];
    const float* b_out = (const float*)d_in[11];
    float* out = (float*)d_out;

    float* xg = (float*)d_ws;                      // 4096*1280 f32
    u16* Xbf = (u16*)(xg + 4096 * XGS);            // 4096*352 u16
    u16* Wihp = Xbf + 4096 * KX;                   // 1280*352 u16
    u16* Wp16 = Wihp + 1280 * KX;                  // 15*80*328 u16
    u16* hb16 = Wp16 + NSLICE * NROWS * LDW;       // 1320960 u16
    u16* Bbf = hb16 + 1320960;                     // 10240000 u16
    int* lvl_nodes = (int*)(Bbf + 10240000);       // 4096 i32
    int* lvl_cnt = lvl_nodes + 4096;               // 4096 i32
    int* lvl_start = lvl_cnt + 4096;               // 4096 i32
    int* lvl_split = lvl_start + 4096;             // 4096 i32
    int* nlev = lvl_split + 4096;                  // 32 i32 (+pad)
    int* lvl_done = nlev + 64;                     // 4096 i32

    k_prelude<<<2048, 256, 0, stream>>>(root_hidden, relations, prev_words, rel_emb, emb,
                                        W_ih, W_hh, parents, hb16, lvl_done, Wihp, Wp16,
                                        Xbf, lvl_nodes, lvl_cnt, lvl_start, lvl_split, nlev);

    k_xgemm_cast<<<832, 256, 0, stream>>>(Xbf, Wihp, b_ih, xg, W_out, Bbf);

    k_scan<<<dim3(NB * NSLICE), dim3(TPBS), 0, stream>>>(
        parents, Wp16, xg, b_hh, root_hidden, hb16,
        lvl_nodes, lvl_cnt, lvl_start, lvl_split, nlev, lvl_done);

    k_gemm<<<dim3(8000), 256, 0, stream>>>(hb16, Bbf, b_out, out);
}

// Round 17
// 328.677 us; speedup vs baseline: 1.3062x; 1.3062x over previous
//
#include <hip/hip_runtime.h>
#include <hip/hip_bf16.h>

typedef unsigned short u16;
typedef unsigned int u32;
typedef unsigned long long u64;
typedef __attribute__((ext_vector_type(8))) short short8;
typedef __attribute__((ext_vector_type(4))) float f32x4;

#define NB 32      // trees
#define NN 128     // nodes per tree
#define HH 300     // hidden
#define NV 32000   // vocab
#define KP 320     // padded K; hb16 row stride
#define KX 352     // padded RD+E
#define XGS 1280   // xg row stride

// scan: 32 trees x 15 slices, level-synchronous, MFMA MV (R11/R12 proven)
#define NSLICE 15
#define UPS 20
#define NROWS 80
#define TPBS 320
#define GMAXN 16
#define LDW 328

#define A_LD(p)     __hip_atomic_load((p), __ATOMIC_RELAXED, __HIP_MEMORY_SCOPE_AGENT)
#define A_ST(p, v)  __hip_atomic_store((p), (v), __ATOMIC_RELAXED, __HIP_MEMORY_SCOPE_AGENT)
#define A_ADD(p, v) __hip_atomic_fetch_add((p), (v), __ATOMIC_RELAXED, __HIP_MEMORY_SCOPE_AGENT)

__device__ __forceinline__ float sigm(float x) { return 1.f / (1.f + __expf(-x)); }
__device__ __forceinline__ float tanh_f(float x) {
    float e = __expf(2.f * x);
    return 1.f - 2.f / (e + 1.f);
}
__device__ __forceinline__ u16 f2bf(float f) {
    __hip_bfloat16 b = __float2bfloat16(f);
    return *reinterpret_cast<u16*>(&b);
}
__device__ __forceinline__ void gl_lds16(const u16* gsrc, u16* ldst) {
    __builtin_amdgcn_global_load_lds(
        (const __attribute__((address_space(1))) void*)gsrc,
        (__attribute__((address_space(3))) void*)ldst, 16, 0, 0);
}

// Merged prelude: hb16 init (pad + roots), lvl_done zero, Wihp pack, Wp16 pack,
// Xbf gather, Bbf cast. All grid-stride; one launch replaces four.
__global__ __launch_bounds__(256) void k_prelude(const float* __restrict__ rh,
                                                 const int* __restrict__ relations,
                                                 const int* __restrict__ prev_words,
                                                 const float* __restrict__ rel_emb,
                                                 const float* __restrict__ emb,
                                                 const float* __restrict__ W_ih,
                                                 const float* __restrict__ W_hh,
                                                 const float* __restrict__ W_out,
                                                 u16* __restrict__ hb16,
                                                 int* __restrict__ lvl_done,
                                                 u16* __restrict__ Wihp,
                                                 u16* __restrict__ Wp16,
                                                 u16* __restrict__ Xbf,
                                                 u16* __restrict__ Bbf) {
    const int stride = gridDim.x * blockDim.x;
    const int idx = blockIdx.x * blockDim.x + threadIdx.x;
    for (int e = idx; e < NB * 129 * 20; e += stride) {
        int row = e / 20, c = 300 + (e - row * 20);
        hb16[(size_t)row * KP + c] = 0;
    }
    for (int e = idx; e < NB * HH; e += stride) {
        int b = e / HH, u = e - b * HH;
        hb16[(size_t)(b * 129) * KP + u] = f2bf(rh[e]);
    }
    for (int e = idx; e < NB * NN; e += stride) lvl_done[e] = 0;
    for (int n = idx; n < 1280 * KX; n += stride) {
        int r = n / KX, k = n - r * KX;
        float v = (r < 1200 && k < 350) ? W_ih[r * 350 + k] : 0.f;
        Wihp[n] = f2bf(v);
    }
    for (int m = idx; m < NSLICE * NROWS * LDW; m += stride) {
        int s = m / (NROWS * LDW);
        int rem = m - s * (NROWS * LDW);
        int r = rem / LDW, k = rem - r * LDW;
        int g = r / UPS, ul = r - g * UPS;
        int grow = g * HH + s * UPS + ul;
        float v = (k < HH) ? W_hh[grow * HH + k] : 0.f;
        Wp16[m] = f2bf(v);
    }
    for (int e = idx; e < NB * NN * KX; e += stride) {
        int node = e / KX, c = e - node * KX;
        float v = 0.f;
        if (c < 50) v = rel_emb[relations[node] * 50 + c];
        else if (c < 350) v = emb[(size_t)prev_words[node] * 300 + (c - 50)];
        Xbf[e] = f2bf(v);
    }
    u64* Bq = (u64*)Bbf;
    for (int e = idx; e < NV * KP / 4; e += stride) {
        const int c4 = e * 4;
        const int v = c4 / KP, k = c4 - v * KP;
        const float* wr = W_out + (size_t)v * HH;
        float x0 = (k + 0 < HH) ? wr[k + 0] : 0.f;
        float x1 = (k + 1 < HH) ? wr[k + 1] : 0.f;
        float x2 = (k + 2 < HH) ? wr[k + 2] : 0.f;
        float x3 = (k + 3 < HH) ? wr[k + 3] : 0.f;
        Bq[e] = (u64)f2bf(x0) | ((u64)f2bf(x1) << 16) |
                ((u64)f2bf(x2) << 32) | ((u64)f2bf(x3) << 48);
    }
}

// per-tree level schedule
__global__ void k_prep(const int* __restrict__ parents, int* __restrict__ lvl_nodes,
                       int* __restrict__ lvl_cnt, int* __restrict__ lvl_start,
                       int* __restrict__ nlev) {
    __shared__ int dep[NB][NN];
    __shared__ int cnt[NB][NN];
    __shared__ int st[NB][NN];
    const int t = threadIdx.x;
    if (t < NB) {
        for (int l = 0; l < NN; ++l) cnt[t][l] = 0;
        int md = 0;
        for (int i = 0; i < NN; ++i) {
            int p = parents[t * NN + i];
            int d = (p < 0) ? 0 : dep[t][p] + 1;
            dep[t][i] = d;
            cnt[t][d]++;
            md = max(md, d);
        }
        nlev[t] = md + 1;
        int run = 0;
        for (int l = 0; l < NN; ++l) {
            st[t][l] = run;
            lvl_start[t * NN + l] = run;
            lvl_cnt[t * NN + l] = cnt[t][l];
            run += cnt[t][l];
        }
        for (int i = 0; i < NN; ++i) {
            int d = dep[t][i];
            lvl_nodes[t * NN + st[t][d]] = i;
            st[t][d]++;
        }
    }
}

// xg[4096][1280] = X @ Wihp^T + b_ih (swapped-MFMA epilogue, f32x4 stores)
__global__ __launch_bounds__(256) void k_xgemm(const u16* __restrict__ Xbf,
                                               const u16* __restrict__ Wihp,
                                               const float* __restrict__ b_ih,
                                               float* __restrict__ xg) {
    __shared__ __align__(16) u16 As[128 * 40];
    __shared__ __align__(16) u16 Bs[128 * 40];
    const int tid = threadIdx.x;
    const int lane = tid & 63, wv = tid >> 6;
    const int wm = wv >> 1, wn = wv & 1;
    const int mblk = blockIdx.x, nblk = blockIdx.y;
    const u16* Ag = Xbf + (size_t)mblk * 128 * KX;
    const u16* Bg = Wihp + (size_t)nblk * 128 * KX;
    f32x4 acc[4][4] = {};
    const int lrow = lane & 15, lseg = lane >> 4;
    for (int kk = 0; kk < KX; kk += 32) {
#pragma unroll
        for (int q = 0; q < 2; ++q) {
            int s = tid + q * 256;
            int r = s >> 2, seg = s & 3;
            *(uint4*)&As[r * 40 + seg * 8] = *(const uint4*)&Ag[(size_t)r * KX + kk + seg * 8];
            *(uint4*)&Bs[r * 40 + seg * 8] = *(const uint4*)&Bg[(size_t)r * KX + kk + seg * 8];
        }
        __syncthreads();
        short8 av[4], bv[4];
#pragma unroll
        for (int i = 0; i < 4; ++i) {
            av[i] = *(const short8*)&As[(wm * 64 + i * 16 + lrow) * 40 + lseg * 8];
            bv[i] = *(const short8*)&Bs[(wn * 64 + i * 16 + lrow) * 40 + lseg * 8];
        }
#pragma unroll
        for (int i = 0; i < 4; ++i)
#pragma unroll
            for (int j = 0; j < 4; ++j)
                acc[i][j] = __builtin_amdgcn_mfma_f32_16x16x32_bf16(bv[j], av[i], acc[i][j],
                                                                    0, 0, 0);
        __syncthreads();
    }
#pragma unroll
    for (int i = 0; i < 4; ++i) {
        const int row = mblk * 128 + wm * 64 + i * 16 + lrow;
        float* orow = xg + (size_t)row * XGS;
#pragma unroll
        for (int j = 0; j < 4; ++j) {
            const int col = nblk * 128 + wn * 64 + j * 16 + lseg * 4;
            f32x4 v = acc[i][j];
            if (col < 1200) {
                f32x4 bo = *(const f32x4*)&b_ih[col];
                v[0] += bo[0]; v[1] += bo[1]; v[2] += bo[2]; v[3] += bo[3];
            }
            *(f32x4*)&orow[col] = v;
        }
    }
}

// Level-synchronous MFMA scan (R11/R12 proven, byte-identical)
__global__ __launch_bounds__(TPBS) void k_scan(const int* __restrict__ parents,
                                               const u16* __restrict__ Wp16,
                                               const float* __restrict__ xg,
                                               const float* __restrict__ b_hh,
                                               const float* __restrict__ rh,
                                               u16* __restrict__ hb16,
                                               const int* __restrict__ lvl_nodes,
                                               const int* __restrict__ lvl_cnt,
                                               const int* __restrict__ lvl_start,
                                               const int* __restrict__ nlev,
                                               int* __restrict__ lvl_done) {
    __shared__ __align__(16) u16 Wl[NROWS * LDW];
    __shared__ __align__(16) u16 hs[GMAXN * LDW];
    __shared__ __align__(16) float gates[GMAXN * 82];
    __shared__ float c_lds[129 * UPS];
    __shared__ int nid_s[GMAXN], par_s[GMAXN];

    const int t = threadIdx.x;
    const int b = blockIdx.x / NSLICE;
    const int s = blockIdx.x % NSLICE;
    const int lane = t & 63, wv = t >> 6;
    const int lrow = lane & 15, lk = lane >> 4;

    {
        const u64* src = (const u64*)(Wp16 + (size_t)s * NROWS * LDW);
        u64* dst = (u64*)Wl;
        for (int e = t; e < NROWS * LDW / 4; e += TPBS) dst[e] = src[e];
    }
    if (t < UPS) c_lds[t] = rh[b * HH + s * UPS + t];
    __syncthreads();

    const int nl = nlev[b];
    for (int l = 0; l < nl; ++l) {
        const int cnt = lvl_cnt[b * NN + l];
        const int start = lvl_start[b * NN + l];
        for (int off = 0; off < cnt; off += GMAXN) {
            const int gc = min(GMAXN, cnt - off);
            if (t < gc) {
                int i = lvl_nodes[b * NN + start + off + t];
                nid_s[t] = i;
                par_s[t] = parents[b * NN + i];
            }
            __syncthreads();
            for (int e = t; e < gc * 80; e += TPBS) {
                const int j = e / 80, q = e - j * 80;
                const u64* hrow = (const u64*)(hb16 +
                    (size_t)(b * 129 + par_s[j] + 1) * KP);
                *(u64*)&hs[j * LDW + q * 4] = A_LD(&hrow[q]);
            }
            __syncthreads();
            {
                f32x4 acc = {};
#pragma unroll
                for (int kk = 0; kk < KP; kk += 32) {
                    short8 av = *(const short8*)&hs[lrow * LDW + kk + lk * 8];
                    short8 bv = *(const short8*)&Wl[(wv * 16 + lrow) * LDW + kk + lk * 8];
                    acc = __builtin_amdgcn_mfma_f32_16x16x32_bf16(av, bv, acc, 0, 0, 0);
                }
#pragma unroll
                for (int r = 0; r < 4; ++r)
                    gates[(lk * 4 + r) * 82 + wv * 16 + lrow] = acc[r];
            }
            __syncthreads();
            if (t < 160) {
                const int j = t / 10, up = t - j * 10;
                if (j < gc) {
                    const int i = nid_s[j];
                    const int par = par_s[j];
                    const int ul0 = up * 2;
                    const float* gj = gates + j * 82;
                    const float* xgp = xg + (size_t)(b * NN + i) * XGS + s * UPS;
                    const float* bhp = b_hh + s * UPS;
                    float hv[2];
#pragma unroll
                    for (int un = 0; un < 2; ++un) {
                        const int ul = ul0 + un;
                        float gs[4];
#pragma unroll
                        for (int g = 0; g < 4; ++g)
                            gs[g] = gj[g * UPS + ul] + xgp[g * HH + ul] + bhp[g * HH + ul];
                        const float pc = c_lds[(par + 1) * UPS + ul];
                        const float cv = sigm(gs[1]) * pc + sigm(gs[0]) * tanh_f(gs[2]);
                        hv[un] = sigm(gs[3]) * tanh_f(cv);
                        c_lds[(i + 1) * UPS + ul] = cv;
                    }
                    const u32 hp = (u32)f2bf(hv[0]) | ((u32)f2bf(hv[1]) << 16);
                    A_ST((u32*)(hb16 + (size_t)(b * 129 + i + 1) * KP + s * UPS + ul0), hp);
                }
            }
            __syncthreads();
        }
        if (l + 1 < nl) {
            if (t == 0) {
                int* dp = &lvl_done[b * NN + l];
                const int old = A_ADD(dp, 1);
                if (old != NSLICE - 1) {
                    while (A_LD(dp) < NSLICE) __builtin_amdgcn_s_sleep(1);
                }
            }
            __syncthreads();
        }
    }
}

// logits = A(hb16) @ B^T + b_out. global_load_lds staging (width 16) with
// both-sides swizzle: linear LDS [128][32]u16, chunk (r,lk) at quad
// q=(lk+(r>>1))&3 (pre-swizzled per-lane global src; same XOR on reads).
// Swapped-MFMA epilogue -> f32x4 nontemporal stores; XCD-swizzled 1D grid.
__global__ __launch_bounds__(256) void k_gemm(const u16* __restrict__ hb16,
                                              const u16* __restrict__ Bbf,
                                              const float* __restrict__ b_out,
                                              float* __restrict__ out) {
    __shared__ __align__(16) u16 As[128 * 32];
    __shared__ __align__(16) u16 Bs[128 * 32];
    const int tid = threadIdx.x;
    const int lane = tid & 63, wv = tid >> 6;
    const int wm = wv >> 1, wn = wv & 1;
    const int bid = blockIdx.x;                  // 8000 = 32 mblk x 250 nblk
    const int newbid = (bid & 7) * 1000 + (bid >> 3);
    const int mblk = newbid & 31, nblk = newbid >> 5;
    const u16* Ag = hb16 + ((size_t)mblk * 129 + 1) * KP;
    const u16* Bg = Bbf + (size_t)nblk * 128 * KP;
    // staging: wave wv covers rows [wv*32, wv*32+32), 2 insts x 16 rows each
    const int r0 = wv * 32 + (lane >> 2);
    const int r1 = r0 + 16;
    const int q0 = lane & 3;
    const int lk0 = (q0 - (r0 >> 1)) & 3;
    const int lk1 = (q0 - (r1 >> 1)) & 3;
    const u16* pa0 = Ag + (size_t)r0 * KP + lk0 * 8;
    const u16* pa1 = Ag + (size_t)r1 * KP + lk1 * 8;
    const u16* pb0 = Bg + (size_t)r0 * KP + lk0 * 8;
    const u16* pb1 = Bg + (size_t)r1 * KP + lk1 * 8;
    u16* lA = As + wv * 1024;   // 2048 B per wave
    u16* lB = Bs + wv * 1024;
    f32x4 acc[4][4] = {};
    const int lrow = lane & 15, lseg = lane >> 4;
    for (int kk = 0; kk < KP; kk += 32) {
        gl_lds16(pa0 + kk, lA);
        gl_lds16(pa1 + kk, lA + 512);
        gl_lds16(pb0 + kk, lB);
        gl_lds16(pb1 + kk, lB + 512);
        __syncthreads();   // drains vmcnt (global_load_lds) for all waves
        short8 av[4], bv[4];
#pragma unroll
        for (int i = 0; i < 4; ++i) {
            const int ra = wm * 64 + i * 16 + lrow;
            const int rb = wn * 64 + i * 16 + lrow;
            av[i] = *(const short8*)&As[ra * 32 + (((lseg + (ra >> 1)) & 3) * 8)];
            bv[i] = *(const short8*)&Bs[rb * 32 + (((lseg + (rb >> 1)) & 3) * 8)];
        }
#pragma unroll
        for (int i = 0; i < 4; ++i)
#pragma unroll
            for (int j = 0; j < 4; ++j)
                acc[i][j] = __builtin_amdgcn_mfma_f32_16x16x32_bf16(bv[j], av[i], acc[i][j],
                                                                    0, 0, 0);
        __syncthreads();
    }
    // swapped layout: row = m (lane&15), cols = n base + (lane>>4)*4 + reg
#pragma unroll
    for (int i = 0; i < 4; ++i) {
        const int row = mblk * 128 + wm * 64 + i * 16 + lrow;
        float* orow = out + (size_t)row * NV;
#pragma unroll
        for (int j = 0; j < 4; ++j) {
            const int col = nblk * 128 + wn * 64 + j * 16 + lseg * 4;
            f32x4 v = acc[i][j];
            f32x4 bo = *(const f32x4*)&b_out[col];
            v[0] += bo[0]; v[1] += bo[1]; v[2] += bo[2]; v[3] += bo[3];
            __builtin_nontemporal_store(v, (f32x4*)&orow[col]);
        }
    }
}

extern "C" void kernel_launch(void* const* d_in, const int* in_sizes, int n_in,
                              void* d_out, int out_size, void* d_ws, size_t ws_size,
                              hipStream_t stream) {
    const float* root_hidden = (const float*)d_in[0];
    const int* relations = (const int*)d_in[1];
    const int* prev_words = (const int*)d_in[2];
    const int* parents = (const int*)d_in[3];
    const float* emb = (const float*)d_in[4];
    const float* rel_emb = (const float*)d_in[5];
    const float* W_ih = (const float*)d_in[6];
    const float* W_hh = (const float*)d_in[7];
    const float* b_ih = (const float*)d_in[8];
    const float* b_hh = (const float*)d_in[9];
    const float* W_out = (const float*)d_in[10];
    const float* b_out = (const float*)d_in[11];
    float* out = (float*)d_out;

    float* xg = (float*)d_ws;                      // 4096*1280 f32
    u16* Xbf = (u16*)(xg + 4096 * XGS);            // 4096*352 u16
    u16* Wihp = Xbf + 4096 * KX;                   // 1280*352 u16
    u16* Wp16 = Wihp + 1280 * KX;                  // 15*80*328 u16
    u16* hb16 = Wp16 + NSLICE * NROWS * LDW;       // 1320960 u16
    u16* Bbf = hb16 + 1320960;                     // 10240000 u16
    int* lvl_nodes = (int*)(Bbf + 10240000);       // 4096 i32
    int* lvl_cnt = lvl_nodes + 4096;               // 4096 i32
    int* lvl_start = lvl_cnt + 4096;               // 4096 i32
    int* nlev = lvl_start + 4096;                  // 32 i32 (+pad)
    int* lvl_done = nlev + 64;                     // 4096 i32

    k_prelude<<<2048, 256, 0, stream>>>(root_hidden, relations, prev_words, rel_emb, emb,
                                        W_ih, W_hh, W_out, hb16, lvl_done, Wihp, Wp16,
                                        Xbf, Bbf);
    k_prep<<<1, 64, 0, stream>>>(parents, lvl_nodes, lvl_cnt, lvl_start, nlev);

    k_xgemm<<<dim3(32, 10), 256, 0, stream>>>(Xbf, Wihp, b_ih, xg);

    k_scan<<<dim3(NB * NSLICE), dim3(TPBS), 0, stream>>>(
        parents, Wp16, xg, b_hh, root_hidden, hb16,
        lvl_nodes, lvl_cnt, lvl_start, nlev, lvl_done);

    k_gemm<<<dim3(8000), 256, 0, stream>>>(hb16, Bbf, b_out, out);
}

// Round 18
// 323.613 us; speedup vs baseline: 1.3266x; 1.0156x over previous
//
#include <hip/hip_runtime.h>
#include <hip/hip_bf16.h>

typedef unsigned short u16;
typedef unsigned int u32;
typedef unsigned long long u64;
typedef __attribute__((ext_vector_type(8))) short short8;
typedef __attribute__((ext_vector_type(4))) float f32x4;

#define NB 32      // trees
#define NN 128     // nodes per tree
#define HH 300     // hidden
#define NV 32000   // vocab
#define KP 320     // padded K; hb16 row stride
#define KX 352     // padded RD+E
#define XGS 1280   // xg row stride

// scan: 32 trees x 15 slices, level-synchronous, MFMA MV (R11-R17 proven)
#define NSLICE 15
#define UPS 20
#define NROWS 80
#define TPBS 320
#define GMAXN 16
#define LDW 328

#define A_LD(p)     __hip_atomic_load((p), __ATOMIC_RELAXED, __HIP_MEMORY_SCOPE_AGENT)
#define A_ST(p, v)  __hip_atomic_store((p), (v), __ATOMIC_RELAXED, __HIP_MEMORY_SCOPE_AGENT)
#define A_ADD(p, v) __hip_atomic_fetch_add((p), (v), __ATOMIC_RELAXED, __HIP_MEMORY_SCOPE_AGENT)

__device__ __forceinline__ float sigm(float x) { return 1.f / (1.f + __expf(-x)); }
__device__ __forceinline__ float tanh_f(float x) {
    float e = __expf(2.f * x);
    return 1.f - 2.f / (e + 1.f);
}
__device__ __forceinline__ u16 f2bf(float f) {
    __hip_bfloat16 b = __float2bfloat16(f);
    return *reinterpret_cast<u16*>(&b);
}
__device__ __forceinline__ void gl_lds16(const u16* gsrc, u16* ldst) {
    __builtin_amdgcn_global_load_lds(
        (const __attribute__((address_space(1))) void*)gsrc,
        (__attribute__((address_space(3))) void*)ldst, 16, 0, 0);
}

// Merged prelude: hb16 init (pad + roots), lvl_done zero, Wihp pack, Wp16 pack,
// Xbf gather, Bbf cast. All grid-stride; one launch replaces four.
__global__ __launch_bounds__(256) void k_prelude(const float* __restrict__ rh,
                                                 const int* __restrict__ relations,
                                                 const int* __restrict__ prev_words,
                                                 const float* __restrict__ rel_emb,
                                                 const float* __restrict__ emb,
                                                 const float* __restrict__ W_ih,
                                                 const float* __restrict__ W_hh,
                                                 const float* __restrict__ W_out,
                                                 u16* __restrict__ hb16,
                                                 int* __restrict__ lvl_done,
                                                 u16* __restrict__ Wihp,
                                                 u16* __restrict__ Wp16,
                                                 u16* __restrict__ Xbf,
                                                 u16* __restrict__ Bbf) {
    const int stride = gridDim.x * blockDim.x;
    const int idx = blockIdx.x * blockDim.x + threadIdx.x;
    for (int e = idx; e < NB * 129 * 20; e += stride) {
        int row = e / 20, c = 300 + (e - row * 20);
        hb16[(size_t)row * KP + c] = 0;
    }
    for (int e = idx; e < NB * HH; e += stride) {
        int b = e / HH, u = e - b * HH;
        hb16[(size_t)(b * 129) * KP + u] = f2bf(rh[e]);
    }
    for (int e = idx; e < NB * NN; e += stride) lvl_done[e] = 0;
    for (int n = idx; n < 1280 * KX; n += stride) {
        int r = n / KX, k = n - r * KX;
        float v = (r < 1200 && k < 350) ? W_ih[r * 350 + k] : 0.f;
        Wihp[n] = f2bf(v);
    }
    for (int m = idx; m < NSLICE * NROWS * LDW; m += stride) {
        int s = m / (NROWS * LDW);
        int rem = m - s * (NROWS * LDW);
        int r = rem / LDW, k = rem - r * LDW;
        int g = r / UPS, ul = r - g * UPS;
        int grow = g * HH + s * UPS + ul;
        float v = (k < HH) ? W_hh[grow * HH + k] : 0.f;
        Wp16[m] = f2bf(v);
    }
    for (int e = idx; e < NB * NN * KX; e += stride) {
        int node = e / KX, c = e - node * KX;
        float v = 0.f;
        if (c < 50) v = rel_emb[relations[node] * 50 + c];
        else if (c < 350) v = emb[(size_t)prev_words[node] * 300 + (c - 50)];
        Xbf[e] = f2bf(v);
    }
    u64* Bq = (u64*)Bbf;
    for (int e = idx; e < NV * KP / 4; e += stride) {
        const int c4 = e * 4;
        const int v = c4 / KP, k = c4 - v * KP;
        const float* wr = W_out + (size_t)v * HH;
        float x0 = (k + 0 < HH) ? wr[k + 0] : 0.f;
        float x1 = (k + 1 < HH) ? wr[k + 1] : 0.f;
        float x2 = (k + 2 < HH) ? wr[k + 2] : 0.f;
        float x3 = (k + 3 < HH) ? wr[k + 3] : 0.f;
        Bq[e] = (u64)f2bf(x0) | ((u64)f2bf(x1) << 16) |
                ((u64)f2bf(x2) << 32) | ((u64)f2bf(x3) << 48);
    }
}

// per-tree level schedule
__global__ void k_prep(const int* __restrict__ parents, int* __restrict__ lvl_nodes,
                       int* __restrict__ lvl_cnt, int* __restrict__ lvl_start,
                       int* __restrict__ nlev) {
    __shared__ int dep[NB][NN];
    __shared__ int cnt[NB][NN];
    __shared__ int st[NB][NN];
    const int t = threadIdx.x;
    if (t < NB) {
        for (int l = 0; l < NN; ++l) cnt[t][l] = 0;
        int md = 0;
        for (int i = 0; i < NN; ++i) {
            int p = parents[t * NN + i];
            int d = (p < 0) ? 0 : dep[t][p] + 1;
            dep[t][i] = d;
            cnt[t][d]++;
            md = max(md, d);
        }
        nlev[t] = md + 1;
        int run = 0;
        for (int l = 0; l < NN; ++l) {
            st[t][l] = run;
            lvl_start[t * NN + l] = run;
            lvl_cnt[t * NN + l] = cnt[t][l];
            run += cnt[t][l];
        }
        for (int i = 0; i < NN; ++i) {
            int d = dep[t][i];
            lvl_nodes[t * NN + st[t][d]] = i;
            st[t][d]++;
        }
    }
}

// xg[4096][1280] = X @ Wihp^T + b_ih (swapped-MFMA epilogue, f32x4 stores)
__global__ __launch_bounds__(256) void k_xgemm(const u16* __restrict__ Xbf,
                                               const u16* __restrict__ Wihp,
                                               const float* __restrict__ b_ih,
                                               float* __restrict__ xg) {
    __shared__ __align__(16) u16 As[128 * 40];
    __shared__ __align__(16) u16 Bs[128 * 40];
    const int tid = threadIdx.x;
    const int lane = tid & 63, wv = tid >> 6;
    const int wm = wv >> 1, wn = wv & 1;
    const int mblk = blockIdx.x, nblk = blockIdx.y;
    const u16* Ag = Xbf + (size_t)mblk * 128 * KX;
    const u16* Bg = Wihp + (size_t)nblk * 128 * KX;
    f32x4 acc[4][4] = {};
    const int lrow = lane & 15, lseg = lane >> 4;
    for (int kk = 0; kk < KX; kk += 32) {
#pragma unroll
        for (int q = 0; q < 2; ++q) {
            int s = tid + q * 256;
            int r = s >> 2, seg = s & 3;
            *(uint4*)&As[r * 40 + seg * 8] = *(const uint4*)&Ag[(size_t)r * KX + kk + seg * 8];
            *(uint4*)&Bs[r * 40 + seg * 8] = *(const uint4*)&Bg[(size_t)r * KX + kk + seg * 8];
        }
        __syncthreads();
        short8 av[4], bv[4];
#pragma unroll
        for (int i = 0; i < 4; ++i) {
            av[i] = *(const short8*)&As[(wm * 64 + i * 16 + lrow) * 40 + lseg * 8];
            bv[i] = *(const short8*)&Bs[(wn * 64 + i * 16 + lrow) * 40 + lseg * 8];
        }
#pragma unroll
        for (int i = 0; i < 4; ++i)
#pragma unroll
            for (int j = 0; j < 4; ++j)
                acc[i][j] = __builtin_amdgcn_mfma_f32_16x16x32_bf16(bv[j], av[i], acc[i][j],
                                                                    0, 0, 0);
        __syncthreads();
    }
#pragma unroll
    for (int i = 0; i < 4; ++i) {
        const int row = mblk * 128 + wm * 64 + i * 16 + lrow;
        float* orow = xg + (size_t)row * XGS;
#pragma unroll
        for (int j = 0; j < 4; ++j) {
            const int col = nblk * 128 + wn * 64 + j * 16 + lseg * 4;
            f32x4 v = acc[i][j];
            if (col < 1200) {
                f32x4 bo = *(const f32x4*)&b_ih[col];
                v[0] += bo[0]; v[1] += bo[1]; v[2] += bo[2]; v[3] += bo[3];
            }
            *(f32x4*)&orow[col] = v;
        }
    }
}

// Level-synchronous MFMA scan. R17 structure; single change: the cell phase's
// xg operands (node-dependent only) are issued into REGISTERS right after the
// ids barrier, concurrent with h staging — hiding their MALL latency under the
// h-stage + MFMA phases. b_hh slice staged to LDS once. Math order identical.
__global__ __launch_bounds__(TPBS) void k_scan(const int* __restrict__ parents,
                                               const u16* __restrict__ Wp16,
                                               const float* __restrict__ xg,
                                               const float* __restrict__ b_hh,
                                               const float* __restrict__ rh,
                                               u16* __restrict__ hb16,
                                               const int* __restrict__ lvl_nodes,
                                               const int* __restrict__ lvl_cnt,
                                               const int* __restrict__ lvl_start,
                                               const int* __restrict__ nlev,
                                               int* __restrict__ lvl_done) {
    __shared__ __align__(16) u16 Wl[NROWS * LDW];
    __shared__ __align__(16) u16 hs[GMAXN * LDW];
    __shared__ __align__(16) float gates[GMAXN * 82];
    __shared__ float c_lds[129 * UPS];
    __shared__ float bh_lds[NROWS];
    __shared__ int nid_s[GMAXN], par_s[GMAXN];

    const int t = threadIdx.x;
    const int b = blockIdx.x / NSLICE;
    const int s = blockIdx.x % NSLICE;
    const int lane = t & 63, wv = t >> 6;
    const int lrow = lane & 15, lk = lane >> 4;

    {
        const u64* src = (const u64*)(Wp16 + (size_t)s * NROWS * LDW);
        u64* dst = (u64*)Wl;
        for (int e = t; e < NROWS * LDW / 4; e += TPBS) dst[e] = src[e];
    }
    if (t < UPS) c_lds[t] = rh[b * HH + s * UPS + t];
    if (t < NROWS) {
        const int g = t / UPS, ul = t - g * UPS;
        bh_lds[t] = b_hh[g * HH + s * UPS + ul];
    }
    __syncthreads();

    // cell-phase thread mapping (fixed): t<160 -> node jj, unit pair up2
    const int jj = t / 10;
    const int up2 = (t - jj * 10) * 2;

    const int nl = nlev[b];
    for (int l = 0; l < nl; ++l) {
        const int cnt = lvl_cnt[b * NN + l];
        const int start = lvl_start[b * NN + l];
        for (int off = 0; off < cnt; off += GMAXN) {
            const int gc = min(GMAXN, cnt - off);
            if (t < gc) {
                int i = lvl_nodes[b * NN + start + off + t];
                nid_s[t] = i;
                par_s[t] = parents[b * NN + i];
            }
            __syncthreads();
            const bool docell = (t < 160) && (jj < gc);
            // issue xg loads early (node-dependent only; lands during h-stage+MFMA)
            float xr[8];
            if (docell) {
                const float* xgp = xg + (size_t)(b * NN + nid_s[jj]) * XGS + s * UPS + up2;
#pragma unroll
                for (int g = 0; g < 4; ++g) {
                    xr[g * 2 + 0] = xgp[g * HH + 0];
                    xr[g * 2 + 1] = xgp[g * HH + 1];
                }
            }
            for (int e = t; e < gc * 80; e += TPBS) {
                const int j = e / 80, q = e - j * 80;
                const u64* hrow = (const u64*)(hb16 +
                    (size_t)(b * 129 + par_s[j] + 1) * KP);
                *(u64*)&hs[j * LDW + q * 4] = A_LD(&hrow[q]);
            }
            __syncthreads();
            {
                f32x4 acc = {};
#pragma unroll
                for (int kk = 0; kk < KP; kk += 32) {
                    short8 av = *(const short8*)&hs[lrow * LDW + kk + lk * 8];
                    short8 bv = *(const short8*)&Wl[(wv * 16 + lrow) * LDW + kk + lk * 8];
                    acc = __builtin_amdgcn_mfma_f32_16x16x32_bf16(av, bv, acc, 0, 0, 0);
                }
#pragma unroll
                for (int r = 0; r < 4; ++r)
                    gates[(lk * 4 + r) * 82 + wv * 16 + lrow] = acc[r];
            }
            __syncthreads();
            if (docell) {
                const int i = nid_s[jj];
                const int par = par_s[jj];
                const float* gj = gates + jj * 82;
                float hv[2];
#pragma unroll
                for (int un = 0; un < 2; ++un) {
                    const int ul = up2 + un;
                    float gs[4];
#pragma unroll
                    for (int g = 0; g < 4; ++g)
                        gs[g] = gj[g * UPS + ul] + xr[g * 2 + un] + bh_lds[g * UPS + ul];
                    const float pc = c_lds[(par + 1) * UPS + ul];
                    const float cv = sigm(gs[1]) * pc + sigm(gs[0]) * tanh_f(gs[2]);
                    hv[un] = sigm(gs[3]) * tanh_f(cv);
                    c_lds[(i + 1) * UPS + ul] = cv;
                }
                const u32 hp = (u32)f2bf(hv[0]) | ((u32)f2bf(hv[1]) << 16);
                A_ST((u32*)(hb16 + (size_t)(b * 129 + i + 1) * KP + s * UPS + up2), hp);
            }
            __syncthreads();  // drains h publishes (vmcnt0) + LDS reuse safety
        }
        if (l + 1 < nl) {
            if (t == 0) {
                int* dp = &lvl_done[b * NN + l];
                const int old = A_ADD(dp, 1);
                if (old != NSLICE - 1) {
                    while (A_LD(dp) < NSLICE) __builtin_amdgcn_s_sleep(1);
                }
            }
            __syncthreads();
        }
    }
}

// logits = A(hb16) @ B^T + b_out — byte-identical to R15/R17's proven kernel.
__global__ __launch_bounds__(256) void k_gemm(const u16* __restrict__ hb16,
                                              const u16* __restrict__ Bbf,
                                              const float* __restrict__ b_out,
                                              float* __restrict__ out) {
    __shared__ __align__(16) u16 As[128 * 32];
    __shared__ __align__(16) u16 Bs[128 * 32];
    const int tid = threadIdx.x;
    const int lane = tid & 63, wv = tid >> 6;
    const int wm = wv >> 1, wn = wv & 1;
    const int bid = blockIdx.x;                  // 8000 = 32 mblk x 250 nblk
    const int newbid = (bid & 7) * 1000 + (bid >> 3);
    const int mblk = newbid & 31, nblk = newbid >> 5;
    const u16* Ag = hb16 + ((size_t)mblk * 129 + 1) * KP;
    const u16* Bg = Bbf + (size_t)nblk * 128 * KP;
    const int r0 = wv * 32 + (lane >> 2);
    const int r1 = r0 + 16;
    const int q0 = lane & 3;
    const int lk0 = (q0 - (r0 >> 1)) & 3;
    const int lk1 = (q0 - (r1 >> 1)) & 3;
    const u16* pa0 = Ag + (size_t)r0 * KP + lk0 * 8;
    const u16* pa1 = Ag + (size_t)r1 * KP + lk1 * 8;
    const u16* pb0 = Bg + (size_t)r0 * KP + lk0 * 8;
    const u16* pb1 = Bg + (size_t)r1 * KP + lk1 * 8;
    u16* lA = As + wv * 1024;
    u16* lB = Bs + wv * 1024;
    f32x4 acc[4][4] = {};
    const int lrow = lane & 15, lseg = lane >> 4;
    for (int kk = 0; kk < KP; kk += 32) {
        gl_lds16(pa0 + kk, lA);
        gl_lds16(pa1 + kk, lA + 512);
        gl_lds16(pb0 + kk, lB);
        gl_lds16(pb1 + kk, lB + 512);
        __syncthreads();
        short8 av[4], bv[4];
#pragma unroll
        for (int i = 0; i < 4; ++i) {
            const int ra = wm * 64 + i * 16 + lrow;
            const int rb = wn * 64 + i * 16 + lrow;
            av[i] = *(const short8*)&As[ra * 32 + (((lseg + (ra >> 1)) & 3) * 8)];
            bv[i] = *(const short8*)&Bs[rb * 32 + (((lseg + (rb >> 1)) & 3) * 8)];
        }
#pragma unroll
        for (int i = 0; i < 4; ++i)
#pragma unroll
            for (int j = 0; j < 4; ++j)
                acc[i][j] = __builtin_amdgcn_mfma_f32_16x16x32_bf16(bv[j], av[i], acc[i][j],
                                                                    0, 0, 0);
        __syncthreads();
    }
#pragma unroll
    for (int i = 0; i < 4; ++i) {
        const int row = mblk * 128 + wm * 64 + i * 16 + lrow;
        float* orow = out + (size_t)row * NV;
#pragma unroll
        for (int j = 0; j < 4; ++j) {
            const int col = nblk * 128 + wn * 64 + j * 16 + lseg * 4;
            f32x4 v = acc[i][j];
            f32x4 bo = *(const f32x4*)&b_out[col];
            v[0] += bo[0]; v[1] += bo[1]; v[2] += bo[2]; v[3] += bo[3];
            __builtin_nontemporal_store(v, (f32x4*)&orow[col]);
        }
    }
}

extern "C" void kernel_launch(void* const* d_in, const int* in_sizes, int n_in,
                              void* d_out, int out_size, void* d_ws, size_t ws_size,
                              hipStream_t stream) {
    const float* root_hidden = (const float*)d_in[0];
    const int* relations = (const int*)d_in[1];
    const int* prev_words = (const int*)d_in[2];
    const int* parents = (const int*)d_in[3];
    const float* emb = (const float*)d_in[4];
    const float* rel_emb = (const float*)d_in[5];
    const float* W_ih = (const float*)d_in[6];
    const float* W_hh = (const float*)d_in[7];
    const float* b_ih = (const float*)d_in[8];
    const float* b_hh = (const float*)d_in[9];
    const float* W_out = (const float*)d_in[10];
    const float* b_out = (const float*)d_in[11];
    float* out = (float*)d_out;

    float* xg = (float*)d_ws;                      // 4096*1280 f32
    u16* Xbf = (u16*)(xg + 4096 * XGS);            // 4096*352 u16
    u16* Wihp = Xbf + 4096 * KX;                   // 1280*352 u16
    u16* Wp16 = Wihp + 1280 * KX;                  // 15*80*328 u16
    u16* hb16 = Wp16 + NSLICE * NROWS * LDW;       // 1320960 u16
    u16* Bbf = hb16 + 1320960;                     // 10240000 u16
    int* lvl_nodes = (int*)(Bbf + 10240000);       // 4096 i32
    int* lvl_cnt = lvl_nodes + 4096;               // 4096 i32
    int* lvl_start = lvl_cnt + 4096;               // 4096 i32
    int* nlev = lvl_start + 4096;                  // 32 i32 (+pad)
    int* lvl_done = nlev + 64;                     // 4096 i32

    k_prelude<<<2048, 256, 0, stream>>>(root_hidden, relations, prev_words, rel_emb, emb,
                                        W_ih, W_hh, W_out, hb16, lvl_done, Wihp, Wp16,
                                        Xbf, Bbf);
    k_prep<<<1, 64, 0, stream>>>(parents, lvl_nodes, lvl_cnt, lvl_start, nlev);

    k_xgemm<<<dim3(32, 10), 256, 0, stream>>>(Xbf, Wihp, b_ih, xg);

    k_scan<<<dim3(NB * NSLICE), dim3(TPBS), 0, stream>>>(
        parents, Wp16, xg, b_hh, root_hidden, hb16,
        lvl_nodes, lvl_cnt, lvl_start, nlev, lvl_done);

    k_gemm<<<dim3(8000), 256, 0, stream>>>(hb16, Bbf, b_out, out);
}